// Round 3
// baseline (633.238 us; speedup 1.0000x reference)
//
#include <hip/hip_runtime.h>
#include <math.h>

#define C 96
#define K 512
#define P_PER_B 110592   // 48*48*48
#define NPOS 221184      // 2 * 110592

// ---------------------------------------------------------------------------
// Strategy: the harness's np reference is an fp32 numpy recompute. argmax on
// near-tie positions depends on its exact rounding, so we must reproduce
// numpy's fp32 arithmetic bit-exactly at any position where the decision is
// close. Fast FMA pass computes best/second; positions with margin <
// 3e-4*||x|| (vs combined rounding noise <1e-5*||x||, >30x safety) are
// re-resolved by an exact numpy-semantics fp32 emulation.
//
// numpy semantics emulated:
//  - prototype norms: contiguous-axis pairwise sum, 8-accumulator pattern
//  - x norms: non-contiguous-axis reduce -> strictly sequential adds
//  - einsum (optimize=False): acc = fadd(acc, fmul(a,b)), c ascending, no FMA
//  - argmax: first occurrence of max
// All via __fmul_rn/__fadd_rn/__fsqrt_rn/__fdiv_rn (contraction-proof).
// ---------------------------------------------------------------------------

// Workspace: pn[512][96] fp32, numpy-exact normalized prototypes (192 KB).

__global__ __launch_bounds__(256) void prep_kernel(const float* __restrict__ proto,
                                                   float* __restrict__ pn) {
    int k = blockIdx.x * 256 + threadIdx.x;
    if (k >= K) return;
    const float* row = proto + k * C;
    // numpy pairwise_sum, n=96 <= blocksize: 8 accumulators + fixed combine
    float r[8];
#pragma unroll
    for (int j = 0; j < 8; ++j) r[j] = __fmul_rn(row[j], row[j]);
    for (int i = 8; i < C; i += 8) {
#pragma unroll
        for (int j = 0; j < 8; ++j)
            r[j] = __fadd_rn(r[j], __fmul_rn(row[i + j], row[i + j]));
    }
    float res = __fadd_rn(__fadd_rn(__fadd_rn(r[0], r[1]), __fadd_rn(r[2], r[3])),
                          __fadd_rn(__fadd_rn(r[4], r[5]), __fadd_rn(r[6], r[7])));
    float n = fmaxf(__fsqrt_rn(res), 1e-12f);
    float* dst = pn + k * C;
    for (int c = 0; c < C; ++c) dst[c] = __fdiv_rn(row[c], n);
}

// ---------------------------------------------------------------------------
// Fast pass: fp32 FMA argmax with margin flag (sign bit). One thread per
// position; x-vector in 96 VGPRs (coalesced). pn reads are wave-uniform.
// ---------------------------------------------------------------------------
__global__ __launch_bounds__(256, 2) void sim_argmax_kernel(
        const float* __restrict__ x,
        const float* __restrict__ pn,
        int* __restrict__ out) {
    int g = blockIdx.x * 256 + threadIdx.x;   // grid exact: g < NPOS
    int b = (g >= P_PER_B) ? 1 : 0;
    int p = g - b * P_PER_B;
    const float* xb = x + (size_t)b * (size_t)C * P_PER_B + p;

    float xr[C];
    float n2 = 0.f;
#pragma unroll
    for (int c = 0; c < C; ++c) {
        xr[c] = xb[(size_t)c * P_PER_B];
        n2 = fmaf(xr[c], xr[c], n2);
    }

    float best = -3.4e38f, second = -3.4e38f;
    int bestk = 0;

#pragma unroll 2
    for (int k = 0; k < K; ++k) {
        const float4* pr = (const float4*)(pn + (size_t)k * C);  // 384B rows, 16B aligned
        float s = 0.f;
#pragma unroll
        for (int c4 = 0; c4 < C / 4; ++c4) {
            float4 q = pr[c4];
            s = fmaf(xr[c4 * 4 + 0], q.x, s);
            s = fmaf(xr[c4 * 4 + 1], q.y, s);
            s = fmaf(xr[c4 * 4 + 2], q.z, s);
            s = fmaf(xr[c4 * 4 + 3], q.w, s);
        }
        if (s > best) {
            second = best;
            best = s;
            bestk = k;
        } else if (s > second) {
            second = s;
        }
    }

    // scores = ||x|| * cos + O(2e-6*||x||); numpy's own noise ~1e-6*||x||.
    float tau = 3e-4f * sqrtf(n2);
    out[g] = (best - second < tau) ? (bestk | (int)0x80000000) : bestk;
}

// ---------------------------------------------------------------------------
// Refine pass: block scans its 256-position stripe; flagged positions are
// re-resolved with the exact numpy-fp32 emulation. Thread t handles
// prototypes t and t+256; LDS tree argmax with first-index tie-break.
// ---------------------------------------------------------------------------
__global__ __launch_bounds__(256) void refine_kernel(
        const float* __restrict__ x,
        const float* __restrict__ pn,
        int* __restrict__ out) {
    __shared__ int list[256];
    __shared__ int cnt;
    __shared__ float xn[C];
    __shared__ float nrm_s;
    __shared__ float sc[256];
    __shared__ int ki[256];

    int tid = threadIdx.x;
    int g = blockIdx.x * 256 + tid;

    if (tid == 0) cnt = 0;
    __syncthreads();

    if (out[g] < 0) {
        int i = atomicAdd(&cnt, 1);
        list[i] = g;
    }
    __syncthreads();
    int n = cnt;

    for (int i = 0; i < n; ++i) {
        int gg = list[i];
        int b = (gg >= P_PER_B) ? 1 : 0;
        int p = gg - b * P_PER_B;
        const float* xb = x + (size_t)b * (size_t)C * P_PER_B + p;

        if (tid < C) xn[tid] = xb[(size_t)tid * P_PER_B];
        __syncthreads();

        // numpy: norm over non-contiguous axis -> strictly sequential fp32
        if (tid == 0) {
            float acc = __fmul_rn(xn[0], xn[0]);
            for (int c = 1; c < C; ++c)
                acc = __fadd_rn(acc, __fmul_rn(xn[c], xn[c]));
            nrm_s = fmaxf(__fsqrt_rn(acc), 1e-12f);
        }
        __syncthreads();
        if (tid < C) xn[tid] = __fdiv_rn(xn[tid], nrm_s);
        __syncthreads();

        // einsum optimize=False: sequential fp32 mul+add, c ascending, no FMA
        const float* pr0 = pn + (size_t)tid * C;
        const float* pr1 = pn + (size_t)(tid + 256) * C;
        float s0 = 0.f, s1 = 0.f;
        for (int c = 0; c < C; ++c) {
            s0 = __fadd_rn(s0, __fmul_rn(xn[c], pr0[c]));
            s1 = __fadd_rn(s1, __fmul_rn(xn[c], pr1[c]));
        }

        float bv = s0;
        int bk = tid;
        if (s1 > bv) { bv = s1; bk = tid + 256; }  // strict: lower index wins ties

        sc[tid] = bv;
        ki[tid] = bk;
        __syncthreads();

        for (int off = 128; off > 0; off >>= 1) {
            if (tid < off) {
                float ov = sc[tid + off];
                int oi = ki[tid + off];
                if (ov > sc[tid] || (ov == sc[tid] && oi < ki[tid])) {
                    sc[tid] = ov;
                    ki[tid] = oi;
                }
            }
            __syncthreads();
        }

        if (tid == 0) out[gg] = ki[0];
        __syncthreads();
    }
}

// ---------------------------------------------------------------------------
extern "C" void kernel_launch(void* const* d_in, const int* in_sizes, int n_in,
                              void* d_out, int out_size, void* d_ws, size_t ws_size,
                              hipStream_t stream) {
    const float* x = (const float*)d_in[0];      // [2,96,48,48,48] fp32
    const float* proto = (const float*)d_in[1];  // [512,96] fp32
    int* out = (int*)d_out;                      // [2,48,48,48] int32

    float* pn = (float*)d_ws;                    // 512*96*4 = 196608 B

    prep_kernel<<<2, 256, 0, stream>>>(proto, pn);
    sim_argmax_kernel<<<NPOS / 256, 256, 0, stream>>>(x, pn, out);
    refine_kernel<<<NPOS / 256, 256, 0, stream>>>(x, pn, out);
}